// Round 7
// baseline (1255.574 us; speedup 1.0000x reference)
//
#include <hip/hip_runtime.h>

#define NPIX (1024 * 1024)
#define NBATCH 16
#define NBINS 8192

typedef float vfloat4 __attribute__((ext_vector_type(4)));

// ---------------------------------------------------------------------------
// Kernel 0: zero the 16 per-batch histograms (512 KB). ~2 us (R0-measured).
// ---------------------------------------------------------------------------
__global__ void zero_kernel(unsigned int* __restrict__ g) {
    int i = blockIdx.x * blockDim.x + threadIdx.x;
    int n = NBATCH * NBINS;
    for (; i < n; i += gridDim.x * blockDim.x) g[i] = 0u;
}

// ---------------------------------------------------------------------------
// Kernel 1: GLOBAL-ATOMIC histogram — no LDS at all.
// R6 post-mortem: hist is pinned at ~90 us (2.3 TB/s) with VALU idle, BW
// unsaturated, and is insensitive to occupancy/ILP/flush -> by elimination
// the serializer is the per-CU LDS atomic unit (16.7M lane-ops at the
// observed rate = 0.3 lanes/cy/CU). The L2 atomic path is measured-fast
// (R0's 8.4M random global atomics were free). So: one fire-and-forget
// global atomicAdd per pixel into the per-batch histogram; blocks shaped
// like apply (256 thr, one-shot, 12 loads in flight, no barriers).
// ---------------------------------------------------------------------------
__global__ __launch_bounds__(256) void hist_kernel(
        const float* __restrict__ img,
        const float* __restrict__ rgb2yuv,
        unsigned int* __restrict__ ghist) {
    const int blocksPerBatch = (NPIX / 4) / 1024;  // 256
    const int b = blockIdx.x / blocksPerBatch;
    const int c = blockIdx.x % blocksPerBatch;
    const float c0 = rgb2yuv[0];
    const float c1 = rgb2yuv[1];
    const float c2 = rgb2yuv[2];

    const size_t base = (size_t)b * 3 * NPIX;
    const float4* r4 = (const float4*)(img + base) + (size_t)c * 1024;
    const float4* g4 = (const float4*)(img + base + NPIX) + (size_t)c * 1024;
    const float4* b4 =
        (const float4*)(img + base + 2 * (size_t)NPIX) + (size_t)c * 1024;
    unsigned int* h = ghist + (size_t)b * NBINS;

    const int t = threadIdx.x;
    // 12 independent loads issued before any compute.
    float4 R0 = r4[t], R1 = r4[t + 256], R2 = r4[t + 512], R3 = r4[t + 768];
    float4 G0 = g4[t], G1 = g4[t + 256], G2 = g4[t + 512], G3 = g4[t + 768];
    float4 B0 = b4[t], B1 = b4[t + 256], B2 = b4[t + 512], B3 = b4[t + 768];

    const float scale = (float)NBINS;
#define HIST4(R, G, B)                                                 \
    {                                                                  \
        float y0 = c0 * R.x + c1 * G.x + c2 * B.x;                     \
        float y1 = c0 * R.y + c1 * G.y + c2 * B.y;                     \
        float y2 = c0 * R.z + c1 * G.z + c2 * B.z;                     \
        float y3 = c0 * R.w + c1 * G.w + c2 * B.w;                     \
        int i0 = min(NBINS - 1, max(0, (int)(y0 * scale)));            \
        int i1 = min(NBINS - 1, max(0, (int)(y1 * scale)));            \
        int i2 = min(NBINS - 1, max(0, (int)(y2 * scale)));            \
        int i3 = min(NBINS - 1, max(0, (int)(y3 * scale)));            \
        atomicAdd(&h[i0], 1u);                                         \
        atomicAdd(&h[i1], 1u);                                         \
        atomicAdd(&h[i2], 1u);                                         \
        atomicAdd(&h[i3], 1u);                                         \
    }
    HIST4(R0, G0, B0);
    HIST4(R1, G1, B1);
    HIST4(R2, G2, B2);
    HIST4(R3, G3, B3);
#undef HIST4
}

// ---------------------------------------------------------------------------
// Kernel 2: one block per batch, reads the final 32 KB histogram, scans,
// locates the 4 order statistics (10485,10486 / 1038089,1038090),
// interpolates within bin, writes (blkpt, mult) per batch.
// ---------------------------------------------------------------------------
__global__ __launch_bounds__(1024) void scan_kernel(
        const unsigned int* __restrict__ ghist,
        float* __restrict__ stats) {
    __shared__ unsigned int hist[NBINS];
    __shared__ unsigned int segsum[1024];
    __shared__ float vals[4];

    const int b = blockIdx.x;
    const int t = threadIdx.x;

    for (int i = t; i < NBINS; i += 1024)
        hist[i] = ghist[(size_t)b * NBINS + i];
    __syncthreads();

    const int BPT = NBINS / 1024;  // 8
    unsigned int ss = 0;
#pragma unroll
    for (int j = 0; j < BPT; ++j) ss += hist[t * BPT + j];
    segsum[t] = ss;
    __syncthreads();

    for (int off = 1; off < 1024; off <<= 1) {
        unsigned int v = segsum[t];
        unsigned int add = (t >= off) ? segsum[t - off] : 0u;
        __syncthreads();
        segsum[t] = v + add;
        __syncthreads();
    }

    const unsigned int cumincl = segsum[t];
    const unsigned int cumbefore = (t > 0) ? segsum[t - 1] : 0u;

    const unsigned int ranks[4] = {10485u, 10486u, 1038089u, 1038090u};
#pragma unroll
    for (int q = 0; q < 4; ++q) {
        unsigned int r = ranks[q];
        if (r >= cumbefore && r < cumincl) {
            unsigned int running = cumbefore;
#pragma unroll
            for (int j = 0; j < BPT; ++j) {
                unsigned int c = hist[t * BPT + j];
                if (r < running + c) {
                    vals[q] = ((float)(t * BPT + j) +
                               ((float)(r - running) + 0.5f) / (float)c) *
                              (1.0f / (float)NBINS);
                    break;
                }
                running += c;
            }
        }
    }
    __syncthreads();

    if (t == 0) {
        float blk = 0.25f * vals[0] + 0.75f * vals[1];
        float wht = 0.75f * vals[2] + 0.25f * vals[3];
        float mult = fminf(1.0f / (wht - blk), 1.5f);
        stats[b * 2 + 0] = blk;
        stats[b * 2 + 1] = mult;
    }
}

// ---------------------------------------------------------------------------
// Kernel 3: out = clip((img - blk[b]) * mult[b], 0, 1). ~45 us inferred
// (near floor: 201 MB write + L3-assisted read). Plain stores (R4 A/B:
// NT == plain). 12288 blocks x 256 thr, 4 float4/thread.
// ---------------------------------------------------------------------------
__global__ __launch_bounds__(256) void apply_kernel(
        const float* __restrict__ img,
        const float* __restrict__ stats,
        float* __restrict__ out) {
    const int blocksPerBatch = (3 * NPIX / 4) / 1024;  // 768
    const int b = blockIdx.x / blocksPerBatch;
    const int c = blockIdx.x % blocksPerBatch;
    const float blk = stats[b * 2 + 0];
    const float mult = stats[b * 2 + 1];

    const vfloat4* in4 =
        (const vfloat4*)(img + (size_t)b * 3 * NPIX) + (size_t)c * 1024;
    vfloat4* out4 = (vfloat4*)(out + (size_t)b * 3 * NPIX) + (size_t)c * 1024;

    const int t = threadIdx.x;
    vfloat4 v0 = in4[t];
    vfloat4 v1 = in4[t + 256];
    vfloat4 v2 = in4[t + 512];
    vfloat4 v3 = in4[t + 768];

#define CLIP1(vv)                                          \
    vv.x = fminf(fmaxf((vv.x - blk) * mult, 0.0f), 1.0f);  \
    vv.y = fminf(fmaxf((vv.y - blk) * mult, 0.0f), 1.0f);  \
    vv.z = fminf(fmaxf((vv.z - blk) * mult, 0.0f), 1.0f);  \
    vv.w = fminf(fmaxf((vv.w - blk) * mult, 0.0f), 1.0f)
    CLIP1(v0);
    CLIP1(v1);
    CLIP1(v2);
    CLIP1(v3);
#undef CLIP1

    out4[t] = v0;
    out4[t + 256] = v1;
    out4[t + 512] = v2;
    out4[t + 768] = v3;
}

extern "C" void kernel_launch(void* const* d_in, const int* in_sizes, int n_in,
                              void* d_out, int out_size, void* d_ws, size_t ws_size,
                              hipStream_t stream) {
    const float* img = (const float*)d_in[0];
    const float* rgb2yuv = (const float*)d_in[1];
    float* out = (float*)d_out;

    // Workspace layout: [0,128): stats (16 * {blk, mult});
    // [256, 256 + 512K): ghist (16 batches x 8192 bins, u32).
    float* stats = (float*)d_ws;
    unsigned int* ghist = (unsigned int*)((char*)d_ws + 256);

    zero_kernel<<<128, 256, 0, stream>>>(ghist);

    const int histBlocks = NBATCH * ((NPIX / 4) / 1024);  // 4096
    hist_kernel<<<histBlocks, 256, 0, stream>>>(img, rgb2yuv, ghist);

    scan_kernel<<<NBATCH, 1024, 0, stream>>>(ghist, stats);

    const int applyBlocks = NBATCH * ((3 * NPIX / 4) / 1024);  // 12288
    apply_kernel<<<applyBlocks, 256, 0, stream>>>(img, stats, out);
}

// Round 8
// 403.810 us; speedup vs baseline: 3.1093x; 3.1093x over previous
//
#include <hip/hip_runtime.h>

#define NPIX (1024 * 1024)
#define NBATCH 16
#define NBINS 8192

typedef float vfloat4 __attribute__((ext_vector_type(4)));

// ---------------------------------------------------------------------------
// Kernel 0: zero the 16 per-batch histograms (512 KB). ~2 us (R0-measured).
// ---------------------------------------------------------------------------
__global__ void zero_kernel(unsigned int* __restrict__ g) {
    int i = blockIdx.x * blockDim.x + threadIdx.x;
    int n = NBATCH * NBINS;
    for (; i < n; i += gridDim.x * blockDim.x) g[i] = 0u;
}

// ---------------------------------------------------------------------------
// Kernel A: compute bin indices, write packed u16 stream (33.5 MB).
// Pure streaming, no LDS, no atomics — isolates the 3-plane read path.
// 4096 blocks x 256 thr; 16 px/thread: 12 float4 loads, 2 uint4 stores.
// ---------------------------------------------------------------------------
__global__ __launch_bounds__(256) void bin_kernel(
        const float* __restrict__ img,
        const float* __restrict__ rgb2yuv,
        unsigned short* __restrict__ bins) {
    const int blocksPerBatch = (NPIX / 4) / 1024;  // 256
    const int b = blockIdx.x / blocksPerBatch;
    const int c = blockIdx.x % blocksPerBatch;
    const float c0 = rgb2yuv[0];
    const float c1 = rgb2yuv[1];
    const float c2 = rgb2yuv[2];

    const size_t base = (size_t)b * 3 * NPIX;
    const float4* r4 = (const float4*)(img + base) + (size_t)c * 1024;
    const float4* g4 = (const float4*)(img + base + NPIX) + (size_t)c * 1024;
    const float4* b4 =
        (const float4*)(img + base + 2 * (size_t)NPIX) + (size_t)c * 1024;

    const int t = threadIdx.x;
    // 12 independent loads issued before any compute.
    float4 R0 = r4[t], R1 = r4[t + 256], R2 = r4[t + 512], R3 = r4[t + 768];
    float4 G0 = g4[t], G1 = g4[t + 256], G2 = g4[t + 512], G3 = g4[t + 768];
    float4 B0 = b4[t], B1 = b4[t + 256], B2 = b4[t + 512], B3 = b4[t + 768];

    const float scale = (float)NBINS;
#define BIN1(R, G, B, comp)                                            \
    min(NBINS - 1,                                                     \
        max(0, (int)((c0 * R.comp + c1 * G.comp + c2 * B.comp) * scale)))
#define PACK4(R, G, B, lo, hi)                                          \
    {                                                                   \
        int i0 = BIN1(R, G, B, x);                                      \
        int i1 = BIN1(R, G, B, y);                                      \
        int i2 = BIN1(R, G, B, z);                                      \
        int i3 = BIN1(R, G, B, w);                                      \
        lo = (unsigned int)i0 | ((unsigned int)i1 << 16);               \
        hi = (unsigned int)i2 | ((unsigned int)i3 << 16);               \
    }
    uint4 o0, o1;
    PACK4(R0, G0, B0, o0.x, o0.y);
    PACK4(R1, G1, B1, o0.z, o0.w);
    PACK4(R2, G2, B2, o1.x, o1.y);
    PACK4(R3, G3, B3, o1.z, o1.w);
#undef PACK4
#undef BIN1

    // 16 u16 bins per thread, contiguous: thread t owns pixels
    // [c*4096 + t*4 .. +4) x4 chunks -> stores laid out to match the loads:
    // pixel index = c*4096 + k*1024 + t*4 + j  (k = chunk 0..3).
    // Write as two uint4 (8 u16 each) at matching offsets.
    uint4* ob = (uint4*)(bins + (size_t)b * NPIX) + (size_t)c * 512;
    // chunk k covers u16 indices k*1024*? -- keep simple: two uint4 per
    // thread at stride 256: store chunk pairs (R0R1 -> o0, R2R3 -> o1).
    ob[t] = o0;          // pixels c*4096 + [t*8 .. t*8+8)  (chunks 0,1)
    ob[t + 256] = o1;    // pixels c*4096 + 2048 + [t*8 .. +8) (chunks 2,3)
}

// ---------------------------------------------------------------------------
// Kernel B: histogram of the dense u16 bin stream. Single coalesced read
// stream (ushort8 per lane), LDS histogram, consecutive-address atomic
// flush (R0<->R1 A/B: free). 1024 blocks x 512 thr = 4 blocks/CU.
// NOTE: bin order within the stream is irrelevant for a histogram, so
// kernel A's store layout doesn't need to match pixel order.
// ---------------------------------------------------------------------------
__global__ __launch_bounds__(512) void hist_kernel(
        const unsigned short* __restrict__ bins,
        unsigned int* __restrict__ ghist) {
    __shared__ unsigned int lh[NBINS];
    for (int i = threadIdx.x; i < NBINS; i += 512) lh[i] = 0;
    __syncthreads();

    const int SUBPB = 64;                 // blocks per batch
    const int b = blockIdx.x / SUBPB;
    const int s = blockIdx.x % SUBPB;
    const int elemsPB = NPIX / SUBPB;     // 16384 u16 per block
    const uint4* src = (const uint4*)(bins + (size_t)b * NPIX) +
                       (size_t)s * (elemsPB / 8);
    const int n8 = elemsPB / 8;           // 2048 ushort8 -> 4 iters of 512

    const int t = threadIdx.x;
#pragma unroll
    for (int k = 0; k < 4; ++k) {
        uint4 v = src[t + k * 512];
        atomicAdd(&lh[v.x & 0xFFFFu], 1u);
        atomicAdd(&lh[v.x >> 16], 1u);
        atomicAdd(&lh[v.y & 0xFFFFu], 1u);
        atomicAdd(&lh[v.y >> 16], 1u);
        atomicAdd(&lh[v.z & 0xFFFFu], 1u);
        atomicAdd(&lh[v.z >> 16], 1u);
        atomicAdd(&lh[v.w & 0xFFFFu], 1u);
        atomicAdd(&lh[v.w >> 16], 1u);
    }
    __syncthreads();

    // Consecutive-address atomic flush into the per-batch histogram.
    unsigned int* dst = ghist + (size_t)b * NBINS;
    for (int i = t; i < NBINS; i += 512) {
        unsigned int v = lh[i];
        if (v) atomicAdd(&dst[i], v);
    }
}

// ---------------------------------------------------------------------------
// Kernel 2: one block per batch, reads the final 32 KB histogram, scans,
// locates the 4 order statistics (10485,10486 / 1038089,1038090),
// interpolates within bin, writes (blkpt, mult) per batch.
// ---------------------------------------------------------------------------
__global__ __launch_bounds__(1024) void scan_kernel(
        const unsigned int* __restrict__ ghist,
        float* __restrict__ stats) {
    __shared__ unsigned int hist[NBINS];
    __shared__ unsigned int segsum[1024];
    __shared__ float vals[4];

    const int b = blockIdx.x;
    const int t = threadIdx.x;

    for (int i = t; i < NBINS; i += 1024)
        hist[i] = ghist[(size_t)b * NBINS + i];
    __syncthreads();

    const int BPT = NBINS / 1024;  // 8
    unsigned int ss = 0;
#pragma unroll
    for (int j = 0; j < BPT; ++j) ss += hist[t * BPT + j];
    segsum[t] = ss;
    __syncthreads();

    for (int off = 1; off < 1024; off <<= 1) {
        unsigned int v = segsum[t];
        unsigned int add = (t >= off) ? segsum[t - off] : 0u;
        __syncthreads();
        segsum[t] = v + add;
        __syncthreads();
    }

    const unsigned int cumincl = segsum[t];
    const unsigned int cumbefore = (t > 0) ? segsum[t - 1] : 0u;

    const unsigned int ranks[4] = {10485u, 10486u, 1038089u, 1038090u};
#pragma unroll
    for (int q = 0; q < 4; ++q) {
        unsigned int r = ranks[q];
        if (r >= cumbefore && r < cumincl) {
            unsigned int running = cumbefore;
#pragma unroll
            for (int j = 0; j < BPT; ++j) {
                unsigned int c = hist[t * BPT + j];
                if (r < running + c) {
                    vals[q] = ((float)(t * BPT + j) +
                               ((float)(r - running) + 0.5f) / (float)c) *
                              (1.0f / (float)NBINS);
                    break;
                }
                running += c;
            }
        }
    }
    __syncthreads();

    if (t == 0) {
        float blk = 0.25f * vals[0] + 0.75f * vals[1];
        float wht = 0.75f * vals[2] + 0.25f * vals[3];
        float mult = fminf(1.0f / (wht - blk), 1.5f);
        stats[b * 2 + 0] = blk;
        stats[b * 2 + 1] = mult;
    }
}

// ---------------------------------------------------------------------------
// Kernel 3: out = clip((img - blk[b]) * mult[b], 0, 1). ~44 us inferred.
// Plain stores (R4 A/B: NT == plain). 12288 blocks x 256 thr.
// ---------------------------------------------------------------------------
__global__ __launch_bounds__(256) void apply_kernel(
        const float* __restrict__ img,
        const float* __restrict__ stats,
        float* __restrict__ out) {
    const int blocksPerBatch = (3 * NPIX / 4) / 1024;  // 768
    const int b = blockIdx.x / blocksPerBatch;
    const int c = blockIdx.x % blocksPerBatch;
    const float blk = stats[b * 2 + 0];
    const float mult = stats[b * 2 + 1];

    const vfloat4* in4 =
        (const vfloat4*)(img + (size_t)b * 3 * NPIX) + (size_t)c * 1024;
    vfloat4* out4 = (vfloat4*)(out + (size_t)b * 3 * NPIX) + (size_t)c * 1024;

    const int t = threadIdx.x;
    vfloat4 v0 = in4[t];
    vfloat4 v1 = in4[t + 256];
    vfloat4 v2 = in4[t + 512];
    vfloat4 v3 = in4[t + 768];

#define CLIP1(vv)                                          \
    vv.x = fminf(fmaxf((vv.x - blk) * mult, 0.0f), 1.0f);  \
    vv.y = fminf(fmaxf((vv.y - blk) * mult, 0.0f), 1.0f);  \
    vv.z = fminf(fmaxf((vv.z - blk) * mult, 0.0f), 1.0f);  \
    vv.w = fminf(fmaxf((vv.w - blk) * mult, 0.0f), 1.0f)
    CLIP1(v0);
    CLIP1(v1);
    CLIP1(v2);
    CLIP1(v3);
#undef CLIP1

    out4[t] = v0;
    out4[t + 256] = v1;
    out4[t + 512] = v2;
    out4[t + 768] = v3;
}

extern "C" void kernel_launch(void* const* d_in, const int* in_sizes, int n_in,
                              void* d_out, int out_size, void* d_ws, size_t ws_size,
                              hipStream_t stream) {
    const float* img = (const float*)d_in[0];
    const float* rgb2yuv = (const float*)d_in[1];
    float* out = (float*)d_out;

    // Workspace layout:
    //   [0, 128):            stats (16 * {blk, mult})
    //   [256, 256+512K):     ghist (16 x 8192 u32)
    //   [1M, 1M+33.5M):      bins  (16 x 1M u16)
    float* stats = (float*)d_ws;
    unsigned int* ghist = (unsigned int*)((char*)d_ws + 256);
    unsigned short* bins = (unsigned short*)((char*)d_ws + (1 << 20));

    zero_kernel<<<128, 256, 0, stream>>>(ghist);

    const int binBlocks = NBATCH * ((NPIX / 4) / 1024);  // 4096
    bin_kernel<<<binBlocks, 256, 0, stream>>>(img, rgb2yuv, bins);

    hist_kernel<<<NBATCH * 64, 512, 0, stream>>>(bins, ghist);

    scan_kernel<<<NBATCH, 1024, 0, stream>>>(ghist, stats);

    const int applyBlocks = NBATCH * ((3 * NPIX / 4) / 1024);  // 12288
    apply_kernel<<<applyBlocks, 256, 0, stream>>>(img, stats, out);
}